// Round 10
// baseline (865.293 us; speedup 1.0000x reference)
//
#include <hip/hip_runtime.h>
#include <hip/hip_bf16.h>
#include <stdint.h>

#define DIM 128
#define HIDDEN 512
#define EPS 1e-5f
#define NCHUNK 16   // 16 chunks x 32 hidden

typedef __attribute__((ext_vector_type(8))) short bf16x8;
typedef __attribute__((ext_vector_type(4))) float f32x4;

__device__ __forceinline__ unsigned short bf16_rn(float f) {
    unsigned u = __builtin_bit_cast(unsigned, f);
    unsigned r = u + 0x7FFFu + ((u >> 16) & 1u);
    return (unsigned short)(r >> 16);
}
// packed RTNE bf16 convert: a -> low 16, b -> high 16 (v_cvt_pk_bf16_f32)
__device__ __forceinline__ unsigned pk_bf16(float a, float b) {
    float2 t; t.x = a; t.y = b;
    __hip_bfloat162 r = __float22bfloat162_rn(t);
    unsigned u;
    __builtin_memcpy(&u, &r, 4);
    return u;
}

// async global->LDS, 16B per lane: dest = ldsbase + lane*16 (wave-uniform base,
// linear dest — the guide-verified m97 pattern; source is lane-linear too)
__device__ __forceinline__ void gload_lds16(const void* g, void* l) {
    __builtin_amdgcn_global_load_lds(
        (const __attribute__((address_space(1))) unsigned int*)g,
        (__attribute__((address_space(3))) unsigned int*)l, 16, 0, 0);
}

// ---------------------------------------------------------------------------
// Prep: single-plane bf16 (1-pass scheme) in MFMA A-operand fragment order:
//   value(frag fi, lane l, j) = W[t*16+(l&15)][ks*32+(l>>4)*8+j]
// w1f: fi = nt*4 + ks   (nt: 32 hidden tiles, ks: 4 k-steps over DIM)  128 KB
// w2f: fi = dt*16 + ks  (dt: 8 out tiles,   ks: 16 k-steps over HIDDEN) 128 KB
// Each fragment = 512 shorts = 1024 B, lane-linear (lane*8 shorts).
// ws usage: 256 KB (< 512 KB proven safe in r2/r5/r8).
// ---------------------------------------------------------------------------
__global__ __launch_bounds__(256) void prep_weights(
    const float* __restrict__ w1, const float* __restrict__ w2,
    unsigned short* __restrict__ w1f, unsigned short* __restrict__ w2f) {
    int idx = blockIdx.x * 256 + threadIdx.x;   // 0 .. 131071
    int o = idx & 65535;
    int j = o & 7;
    int l = (o >> 3) & 63;
    int fi = o >> 9;
    if (idx < 65536) {
        int ks = fi & 3, t = fi >> 2;
        int row = t * 16 + (l & 15);
        int col = ks * 32 + (l >> 4) * 8 + j;
        w1f[o] = bf16_rn(w1[row * DIM + col]);
    } else {
        int ks = fi & 15, t = fi >> 4;
        int row = t * 16 + (l & 15);
        int col = ks * 32 + (l >> 4) * 8 + j;
        w2f[o] = bf16_rn(w2[row * HIDDEN + col]);
    }
}

// slot s (0..15) -> source fragment for chunk c
__device__ __forceinline__ const unsigned short* slot_src(
    const unsigned short* __restrict__ w1f,
    const unsigned short* __restrict__ w2f, int s, int c) {
    if (s < 8) {    // GEMM1 slot: s = ntl*4 + ks
        int ntl = s >> 2, ks = s & 3;
        return w1f + ((size_t)((c * 2 + ntl) * 4 + ks)) * 512;
    } else {        // GEMM2 slot: 8 + dt
        int dt = s - 8;
        return w2f + ((size_t)(dt * 16 + c)) * 512;
    }
}

// stage one 16 KB chunk (16 slots x 1 KB); wave wid stages slots [wid*4, wid*4+4)
__device__ __forceinline__ void stage_chunk(
    const unsigned short* __restrict__ w1f,
    const unsigned short* __restrict__ w2f,
    char* buf, int c, int wid, int lane) {
    #pragma unroll
    for (int i = 0; i < 4; ++i) {
        const int s = wid * 4 + i;
        gload_lds16(slot_src(w1f, w2f, s, c) + lane * 8, buf + s * 1024);
    }
}

// ---------------------------------------------------------------------------
// Fused LN -> Linear -> ReLU -> Linear, plain bf16 1-pass MFMA (both GEMMs).
// 4 waves/block, wave owns 32 tokens. Weights shared block-wide via a
// SINGLE-buffered 16 KB LDS stage (TLP across 6 blocks/CU hides the DMA
// window; dbuf dropped to cut LDS 40->24 KB = 6 blocks/CU, 24 waves):
//   prologue: stage(0); phase1(LN); barrier;
//   loop c: compute from buf; barrier; stage(c+1); barrier;
// LDS: 16 KB weights + 4x2 KB h-bounce = 24 KB.
// ---------------------------------------------------------------------------
__global__ __launch_bounds__(256, 6) void fused_mlp(
    const float* __restrict__ x,
    const unsigned short* __restrict__ w1f,
    const unsigned short* __restrict__ w2f,
    const float* __restrict__ b1, const float* __restrict__ b2,
    const float* __restrict__ wn, const float* __restrict__ bn,
    float* __restrict__ out) {

    __shared__ __align__(16) char lds[24576];
    const int tid  = threadIdx.x;
    const int wid  = tid >> 6;
    const int lane = tid & 63;
    const int g    = lane >> 4;    // k-group 0..3
    const int li   = lane & 15;
    char* hbase = lds + 16384 + wid * 2048;   // per-wave h bounce (single plane)

    const int tok_base = blockIdx.x * 128 + wid * 32;

    // issue chunk-0 weight DMA immediately; latency hides under phase 1
    stage_chunk(w1f, w2f, lds, 0, wid, lane);

    // ---- Phase 1: direct-load LN -> in-register bf16 MFMA fragments.
    // Lane (li,g) owns token (tok_base + mt*16 + li), cols {ks*32 + g*8 + j}.
    bf16x8 xf[2][4];
    {
        f32x4 wnv[4][2], bnv[4][2];
        #pragma unroll
        for (int ks = 0; ks < 4; ++ks) {
            #pragma unroll
            for (int h = 0; h < 2; ++h) {
                wnv[ks][h] = *(const f32x4*)(wn + ks * 32 + g * 8 + h * 4);
                bnv[ks][h] = *(const f32x4*)(bn + ks * 32 + g * 8 + h * 4);
            }
        }
        #pragma unroll
        for (int mt = 0; mt < 2; ++mt) {
            const float* xr = x + (size_t)(tok_base + mt * 16 + li) * DIM;
            f32x4 v[4][2];
            float s = 0.f, q = 0.f;
            #pragma unroll
            for (int ks = 0; ks < 4; ++ks) {
                #pragma unroll
                for (int h = 0; h < 2; ++h) {
                    v[ks][h] = *(const f32x4*)(xr + ks * 32 + g * 8 + h * 4);
                    #pragma unroll
                    for (int j = 0; j < 4; ++j) {
                        s += v[ks][h][j];
                        q += v[ks][h][j] * v[ks][h][j];
                    }
                }
            }
            s += __shfl_xor(s, 16, 64); q += __shfl_xor(q, 16, 64);
            s += __shfl_xor(s, 32, 64); q += __shfl_xor(q, 32, 64);
            float mean = s * (1.0f / 128.0f);
            float var  = q * (1.0f / 128.0f) - mean * mean;
            float rstd = rsqrtf(var + EPS);
            #pragma unroll
            for (int ks = 0; ks < 4; ++ks) {
                unsigned hw[4];
                #pragma unroll
                for (int h = 0; h < 2; ++h) {
                    #pragma unroll
                    for (int jj = 0; jj < 2; ++jj) {
                        float y0 = (v[ks][h][jj * 2]     - mean) * rstd * wnv[ks][h][jj * 2]     + bnv[ks][h][jj * 2];
                        float y1 = (v[ks][h][jj * 2 + 1] - mean) * rstd * wnv[ks][h][jj * 2 + 1] + bnv[ks][h][jj * 2 + 1];
                        hw[h * 2 + jj] = pk_bf16(y0, y1);
                    }
                }
                __builtin_memcpy(&xf[mt][ks], hw, 16);
            }
        }
    }

    __syncthreads();   // drains vmcnt -> chunk-0 weights resident in buf

    f32x4 acc2[8][2];
    #pragma unroll
    for (int dt = 0; dt < 8; ++dt)
        #pragma unroll
        for (int mt = 0; mt < 2; ++mt)
            acc2[dt][mt] = (f32x4){0.f, 0.f, 0.f, 0.f};

    char* buf = lds;
    for (int c = 0; c < NCHUNK; ++c) {
        // --- GEMM1 (1-pass) + bias + ReLU + store h (single bf16 plane)
        #pragma unroll
        for (int ntl = 0; ntl < 2; ++ntl) {
            bf16x8 wfr[4];
            #pragma unroll
            for (int ks = 0; ks < 4; ++ks)
                wfr[ks] = *(const bf16x8*)(buf + (ntl * 4 + ks) * 1024 + lane * 16);
            f32x4 acc1[2];
            acc1[0] = (f32x4){0.f, 0.f, 0.f, 0.f};
            acc1[1] = (f32x4){0.f, 0.f, 0.f, 0.f};
            #pragma unroll
            for (int ks = 0; ks < 4; ++ks) {
                #pragma unroll
                for (int mt = 0; mt < 2; ++mt)
                    acc1[mt] = __builtin_amdgcn_mfma_f32_16x16x32_bf16(wfr[ks], xf[mt][ks], acc1[mt], 0, 0, 0);
            }
            f32x4 b1v = *(const f32x4*)(b1 + c * 32 + ntl * 16 + g * 4);
            #pragma unroll
            for (int mt = 0; mt < 2; ++mt) {
                unsigned hw[2];
                #pragma unroll
                for (int rr = 0; rr < 2; ++rr) {
                    float v0 = fmaxf(acc1[mt][rr * 2]     + b1v[rr * 2],     0.f);
                    float v1 = fmaxf(acc1[mt][rr * 2 + 1] + b1v[rr * 2 + 1], 0.f);
                    hw[rr] = pk_bf16(v0, v1);
                }
                int row  = mt * 16 + li;
                int byte = (row * 64 + ntl * 32 + g * 8) ^ (((row >> 1) & 3) << 4);
                *(uint2*)(hbase + byte) = make_uint2(hw[0], hw[1]);
            }
        }
        // --- read h fragments (B-operand of GEMM2)
        bf16x8 hf[2];
        #pragma unroll
        for (int mt = 0; mt < 2; ++mt) {
            int row  = mt * 16 + li;
            int byte = (row * 64 + g * 16) ^ (((row >> 1) & 3) << 4);
            hf[mt] = *(const bf16x8*)(hbase + byte);
        }
        // --- GEMM2 (1-pass), accumulate C2^T
        #pragma unroll
        for (int dt = 0; dt < 8; ++dt) {
            const bf16x8 w2v = *(const bf16x8*)(buf + (8 + dt) * 1024 + lane * 16);
            #pragma unroll
            for (int mt = 0; mt < 2; ++mt)
                acc2[dt][mt] = __builtin_amdgcn_mfma_f32_16x16x32_bf16(w2v, hf[mt], acc2[dt][mt], 0, 0, 0);
        }
        __syncthreads();   // all waves done reading buf for chunk c
        if (c + 1 < NCHUNK)
            stage_chunk(w1f, w2f, buf, c + 1, wid, lane);
        __syncthreads();   // staged chunk c+1 visible (drains DMA vmcnt)
    }

    // ---- Phase 3: epilogue, +b2, dwordx4 stores (lane holds 4 consecutive d)
    #pragma unroll
    for (int dt = 0; dt < 8; ++dt) {
        f32x4 b2v = *(const f32x4*)(b2 + dt * 16 + g * 4);
        #pragma unroll
        for (int mt = 0; mt < 2; ++mt) {
            f32x4 v = acc2[dt][mt] + b2v;
            int tok = tok_base + mt * 16 + li;
            *(f32x4*)(out + (size_t)tok * DIM + dt * 16 + g * 4) = v;
        }
    }
}

extern "C" void kernel_launch(void* const* d_in, const int* in_sizes, int n_in,
                              void* d_out, int out_size, void* d_ws, size_t ws_size,
                              hipStream_t stream) {
    const float* x  = (const float*)d_in[0];
    const float* w1 = (const float*)d_in[1];
    const float* w2 = (const float*)d_in[2];
    const float* b1 = (const float*)d_in[3];
    const float* b2 = (const float*)d_in[4];
    const float* wn = (const float*)d_in[5];
    const float* bn = (const float*)d_in[6];
    float* out = (float*)d_out;

    unsigned short* w1f = (unsigned short*)d_ws;                 // 128 KB
    unsigned short* w2f = w1f + 65536;                           // 128 KB

    prep_weights<<<512, 256, 0, stream>>>(w1, w2, w1f, w2f);
    fused_mlp<<<2048, 256, 0, stream>>>(x, w1f, w2f, b1, b2, wn, bn, out);
}